// Round 10
// baseline (692.568 us; speedup 1.0000x reference)
//
#include <hip/hip_runtime.h>
#include <hip/hip_bf16.h>

// LightGCN encoder — round 10 (round 9 + compile fix):
//   * nontemporal store/load use unsigned long long (builtin rejects int2*)
//   * partition: 1024-thread blocks, EPT 16 -> same 16384-edge tile (keeps
//     round-8's minimal write-amp) with 4x waves in flight (round-8 lesson)
//   * rows register-cached across phases; val quantized to 14b in partition
//   * keep: fused copy_hist, 4B packed edges, spmm main/tail + 32-bit
//     addressing, fused final mean
//
// d_out layout (floats):
//   [0 .. 9.6M)    : final (users ‖ items)
//   [9.6M .. 48M)  : stacked slots 0..3 -- slot1/2 double as `part` scratch
// d_ws: row_ptr | col_val(u32) | bucket_cnt | bucket_base | bucket_cursor | xq0 | xq1

constexpr int N_USERS = 100000;
constexpr int N_ITEMS = 50000;
constexpr int N_NODES = N_USERS + N_ITEMS;   // 150000
constexpr int EMB     = 64;
constexpr int NNZ     = 6000000;
constexpr long long NODE_ELEMS = (long long)N_NODES * EMB;  // 9,600,000
constexpr float SCALE     = 64.0f;
constexpr float INV_SCALE = 1.0f / 64.0f;
constexpr float VMAX      = 0.05f;
constexpr float VENC      = 16383.0f / VMAX;
constexpr float VDEC      = VMAX / 16383.0f;

constexpr int BSHIFT = 10;                    // 1024 rows per bucket
constexpr int BROWS  = 1 << BSHIFT;           // 1024
constexpr int NBUCK  = (N_NODES + BROWS - 1) / BROWS;  // 147

constexpr int COPY_BLOCKS = (int)((NODE_ELEMS / 4 + 255) / 256);   // 9375
constexpr int HIST_EPT = 16;
constexpr int HIST_BLOCKS = (NNZ + 256 * HIST_EPT - 1) / (256 * HIST_EPT);  // 1465

// ---- fp8 e4m3 pack/unpack via gfx950 HW converts ----
__device__ __forceinline__ unsigned int enc_fp8x4(float a, float b, float c, float d) {
    int r = 0;
    r = __builtin_amdgcn_cvt_pk_fp8_f32(a, b, r, false);
    r = __builtin_amdgcn_cvt_pk_fp8_f32(c, d, r, true);
    return (unsigned int)r;
}
__device__ __forceinline__ float4 dec_fp8x4(unsigned int u) {
    auto lo = __builtin_amdgcn_cvt_pk_f32_fp8((int)u, false);
    auto hi = __builtin_amdgcn_cvt_pk_f32_fp8((int)u, true);
    return make_float4(lo[0], lo[1], hi[0], hi[1]);
}

// ---- zero the bucket counters ----
__global__ void zero_buckets_kernel(int* __restrict__ p) {
    int t = threadIdx.x;
    if (t < NBUCK) p[t] = 0;
}

// ---- fused: emb0 copy (+fp8 encode) ‖ bucket histogram ----
__global__ void copy_hist_kernel(const float* __restrict__ user_emb,
                                 const float* __restrict__ item_emb,
                                 float* __restrict__ slot0,
                                 unsigned int* __restrict__ xq0,
                                 const int* __restrict__ rows,
                                 int* __restrict__ bucket_cnt) {
    if (blockIdx.x < COPY_BLOCKS) {
        long long i4 = (long long)blockIdx.x * 256 + threadIdx.x;
        long long n4 = NODE_ELEMS / 4;
        if (i4 >= n4) return;
        long long i = i4 * 4;
        const long long user_elems = (long long)N_USERS * EMB;
        float4 v;
        if (i < user_elems) {
            v = *reinterpret_cast<const float4*>(user_emb + i);
        } else {
            v = *reinterpret_cast<const float4*>(item_emb + (i - user_elems));
        }
        *reinterpret_cast<float4*>(slot0 + i) = v;
        xq0[i4] = enc_fp8x4(v.x * SCALE, v.y * SCALE, v.z * SCALE, v.w * SCALE);
    } else {
        __shared__ int lcnt[NBUCK];
        int bid = blockIdx.x - COPY_BLOCKS;
        int tid = threadIdx.x;
        for (int i = tid; i < NBUCK; i += 256) lcnt[i] = 0;
        __syncthreads();
        long long base = (long long)bid * 256 * HIST_EPT;
        for (int k = 0; k < HIST_EPT; ++k) {
            long long e = base + (long long)k * 256 + tid;
            if (e < NNZ) atomicAdd(&lcnt[rows[e] >> BSHIFT], 1);
        }
        __syncthreads();
        for (int i = tid; i < NBUCK; i += 256) {
            int c = lcnt[i];
            if (c) atomicAdd(&bucket_cnt[i], c);
        }
    }
}

// ---- bucket scan: base/cursor init + row_ptr[N_NODES] ----
__global__ void bucket_scan_kernel(const int* __restrict__ bucket_cnt,
                                   int* __restrict__ bucket_base,
                                   int* __restrict__ bucket_cursor,
                                   int* __restrict__ row_ptr) {
    __shared__ int s[256];
    int t = threadIdx.x;
    s[t] = (t < NBUCK) ? bucket_cnt[t] : 0;
    __syncthreads();
    int orig = s[t];
    for (int off = 1; off < 256; off <<= 1) {
        int v = (t >= off) ? s[t - off] : 0;
        __syncthreads();
        s[t] += v;
        __syncthreads();
    }
    int excl = s[t] - orig;
    if (t < NBUCK) {
        bucket_base[t] = excl;
        bucket_cursor[t] = excl;
    }
    if (t == NBUCK - 1) bucket_base[NBUCK] = s[t];
    if (t == 0) row_ptr[N_NODES] = NNZ;
}

// ---- pass A: multi-split partition into row-buckets ----
// part[] entry (u64): low32 = (rowoff<<18) | col, high32 = q (14-bit val)
// tile = 16384 edges (minimal write-amp, round 8) via 1024 thr x EPT 16 (TLP)
constexpr int PART_T   = 1024;
constexpr int PART_EPT = 16;
__global__ __launch_bounds__(PART_T) void partition_kernel(
        const int* __restrict__ rows,
        const int* __restrict__ cols,
        const float* __restrict__ vals,
        int* __restrict__ bucket_cursor,
        unsigned long long* __restrict__ part) {
    __shared__ int lcnt[NBUCK];
    __shared__ int lcur[NBUCK];
    int tid = threadIdx.x;
    for (int i = tid; i < NBUCK; i += PART_T) lcnt[i] = 0;
    __syncthreads();
    long long tbase = (long long)blockIdx.x * PART_T * PART_EPT;
    int rloc[PART_EPT];
#pragma unroll
    for (int k = 0; k < PART_EPT; ++k) {
        long long e = tbase + (long long)k * PART_T + tid;
        int r = (e < NNZ) ? rows[e] : -1;
        rloc[k] = r;
        if (r >= 0) atomicAdd(&lcnt[r >> BSHIFT], 1);
    }
    __syncthreads();
    for (int i = tid; i < NBUCK; i += PART_T) {
        lcur[i] = atomicAdd(&bucket_cursor[i], lcnt[i]);
    }
    __syncthreads();
#pragma unroll
    for (int k = 0; k < PART_EPT; ++k) {
        int r = rloc[k];
        if (r < 0) continue;
        long long e = tbase + (long long)k * PART_T + tid;
        int b = r >> BSHIFT;
        int pos = atomicAdd(&lcur[b], 1);
        unsigned int w0 = ((unsigned int)(r & (BROWS - 1)) << 18) | (unsigned int)cols[e];
        unsigned int q = (unsigned int)(int)(fminf(fmaxf(vals[e] * VENC + 0.5f, 0.0f), 16383.0f));
        unsigned long long w = ((unsigned long long)q << 32) | (unsigned long long)w0;
        __builtin_nontemporal_store(w, &part[pos]);
    }
}

// ---- pass B: per-bucket counting sort -> final CSR (packed 4B edges) ----
__global__ __launch_bounds__(BROWS) void bucket_sort_kernel(
        const int* __restrict__ bucket_base,
        const unsigned long long* __restrict__ part,
        int* __restrict__ row_ptr,
        unsigned int* __restrict__ col_val) {
    __shared__ int lcnt[BROWS];
    __shared__ int lcur[BROWS];
    int b = blockIdx.x;
    int t = threadIdx.x;
    int base = bucket_base[b];
    int n    = bucket_base[b + 1] - base;
    lcnt[t] = 0;
    __syncthreads();
    for (int j = t; j < n; j += BROWS) {
        unsigned int w0 = (unsigned int)__builtin_nontemporal_load(&part[base + j]);
        atomicAdd(&lcnt[w0 >> 18], 1);
    }
    __syncthreads();
    int orig = lcnt[t];
    for (int off = 1; off < BROWS; off <<= 1) {
        int v = (t >= off) ? lcnt[t - off] : 0;
        __syncthreads();
        lcnt[t] += v;
        __syncthreads();
    }
    int excl = lcnt[t] - orig;
    int gr = b * BROWS + t;
    if (gr < N_NODES) row_ptr[gr] = base + excl;
    lcur[t] = base + excl;
    __syncthreads();
    for (int j = t; j < n; j += BROWS) {
        unsigned long long w = part[base + j];
        unsigned int w0 = (unsigned int)w;
        unsigned int q  = (unsigned int)(w >> 32);
        int rowoff = (int)(w0 >> 18);
        unsigned int col = w0 & 0x3FFFFu;
        int pos = atomicAdd(&lcur[rowoff], 1);
        col_val[pos] = (col << 14) | q;
    }
}

// ---- pull-based CSR SpMM, fp8 gathers, main/tail split, f32 accumulate ----
// wave per row; lane = (edge-slot g 0..3, dim-word d4 0..15)
// If `fin` != nullptr (layer 3): also compute final = (s0+s1+s2+y)/4.
__global__ void spmm_fp8_kernel(const int* __restrict__ row_ptr,
                                const unsigned int* __restrict__ col_val,
                                const unsigned int* __restrict__ xq_in,  // 16 words/row
                                float* __restrict__ y,
                                unsigned int* __restrict__ xq_out,
                                const float4* __restrict__ s0,
                                const float4* __restrict__ s1,
                                const float4* __restrict__ s2,
                                float4* __restrict__ fin) {
    int row = blockIdx.x * (blockDim.x >> 6) + (threadIdx.x >> 6);
    int lane = threadIdx.x & 63;
    int g  = lane >> 4;   // edge sub-slot
    int d4 = lane & 15;   // 4-dim word index
    if (row >= N_NODES) return;
    int s = row_ptr[row];
    int e = row_ptr[row + 1];
    float4 acc = make_float4(0.f, 0.f, 0.f, 0.f);
    int i = s;
    // main: full 32-edge iterations, no bounds checks
    for (; i + 32 <= e; i += 32) {
        unsigned int cv[8];
        unsigned int q[8];
#pragma unroll
        for (int k = 0; k < 8; ++k) cv[k] = col_val[i + 4 * k + g];
#pragma unroll
        for (int k = 0; k < 8; ++k) q[k] = xq_in[((cv[k] >> 14) << 4) | d4];
#pragma unroll
        for (int k = 0; k < 8; ++k) {
            float v = (float)(cv[k] & 0x3FFFu) * VDEC;
            float4 x = dec_fp8x4(q[k]);
            acc.x += v * x.x; acc.y += v * x.y; acc.z += v * x.z; acc.w += v * x.w;
        }
    }
    // tail: 16-edge iterations, predicated (dummy slots read row 0, val 0)
    for (; i < e; i += 16) {
        unsigned int cv[4];
        unsigned int q[4];
#pragma unroll
        for (int k = 0; k < 4; ++k) {
            int idx = i + 4 * k + g;
            cv[k] = (idx < e) ? col_val[idx] : 0u;
        }
#pragma unroll
        for (int k = 0; k < 4; ++k) q[k] = xq_in[((cv[k] >> 14) << 4) | d4];
#pragma unroll
        for (int k = 0; k < 4; ++k) {
            float v = (float)(cv[k] & 0x3FFFu) * VDEC;
            float4 x = dec_fp8x4(q[k]);
            acc.x += v * x.x; acc.y += v * x.y; acc.z += v * x.z; acc.w += v * x.w;
        }
    }
    // sum the 4 edge-slot partials (lanes differing in bits 4,5)
    acc.x += __shfl_xor(acc.x, 16); acc.y += __shfl_xor(acc.y, 16);
    acc.z += __shfl_xor(acc.z, 16); acc.w += __shfl_xor(acc.w, 16);
    acc.x += __shfl_xor(acc.x, 32); acc.y += __shfl_xor(acc.y, 32);
    acc.z += __shfl_xor(acc.z, 32); acc.w += __shfl_xor(acc.w, 32);
    if (g == 0) {
        long long o = (long long)row * 16 + d4;  // float4 index
        float4 r;
        r.x = acc.x * INV_SCALE;
        r.y = acc.y * INV_SCALE;
        r.z = acc.z * INV_SCALE;
        r.w = acc.w * INV_SCALE;
        reinterpret_cast<float4*>(y)[o] = r;
        if (xq_out) xq_out[o] = enc_fp8x4(acc.x, acc.y, acc.z, acc.w);
        if (fin) {
            float4 a = s0[o], b = s1[o], c = s2[o];
            float4 f;
            f.x = (a.x + b.x + c.x + r.x) * 0.25f;
            f.y = (a.y + b.y + c.y + r.y) * 0.25f;
            f.z = (a.z + b.z + c.z + r.z) * 0.25f;
            f.w = (a.w + b.w + c.w + r.w) * 0.25f;
            fin[o] = f;
        }
    }
}

extern "C" void kernel_launch(void* const* d_in, const int* in_sizes, int n_in,
                              void* d_out, int out_size, void* d_ws, size_t ws_size,
                              hipStream_t stream) {
    const float* user_emb = (const float*)d_in[0];
    const float* item_emb = (const float*)d_in[1];
    const int*   adj_rows = (const int*)d_in[2];
    const int*   adj_cols = (const int*)d_in[3];
    const float* adj_vals = (const float*)d_in[4];

    float* out = (float*)d_out;
    float* final_emb = out;
    float* stacked   = out + NODE_ELEMS;
    float* slot[4];
    for (int l = 0; l < 4; ++l) slot[l] = stacked + (long long)l * NODE_ELEMS;

    // `part` buffer (48MB) aliases slot1+slot2 (76.8MB), dead until SpMM layer 0
    unsigned long long* part = (unsigned long long*)slot[1];

    // workspace carve-up (16B-aligned)
    size_t off = 0;
    auto carve = [&](size_t bytes) { size_t o = off; off += (bytes + 15) & ~(size_t)15; return o; };
    size_t o_rp = carve((size_t)(N_NODES + 1) * 4);
    size_t o_cv = carve((size_t)NNZ * 4);
    size_t o_bc = carve((size_t)NBUCK * 4);
    size_t o_bb = carve((size_t)(NBUCK + 1) * 4);
    size_t o_bu = carve((size_t)NBUCK * 4);
    size_t o_x0 = carve((size_t)(NODE_ELEMS / 4) * 4);
    size_t o_x1 = carve((size_t)(NODE_ELEMS / 4) * 4);
    char* ws = (char*)d_ws;
    int*          row_ptr       = (int*)(ws + o_rp);
    unsigned int* col_val       = (unsigned int*)(ws + o_cv);
    int*          bucket_cnt    = (int*)(ws + o_bc);
    int*          bucket_base   = (int*)(ws + o_bb);
    int*          bucket_cursor = (int*)(ws + o_bu);
    unsigned int* xq[2];
    xq[0] = (unsigned int*)(ws + o_x0);
    xq[1] = (unsigned int*)(ws + o_x1);

    const int B = 256;

    // zero bucket counters, then fused emb0-copy ‖ bucket histogram
    zero_buckets_kernel<<<1, 256, 0, stream>>>(bucket_cnt);
    copy_hist_kernel<<<COPY_BLOCKS + HIST_BLOCKS, B, 0, stream>>>(
        user_emb, item_emb, slot[0], xq[0], adj_rows, bucket_cnt);

    // scan -> partition -> per-bucket sort
    bucket_scan_kernel<<<1, 256, 0, stream>>>(bucket_cnt, bucket_base, bucket_cursor, row_ptr);
    const int part_grid = (NNZ + PART_T * PART_EPT - 1) / (PART_T * PART_EPT);
    partition_kernel<<<part_grid, PART_T, 0, stream>>>(
        adj_rows, adj_cols, adj_vals, bucket_cursor, part);
    bucket_sort_kernel<<<NBUCK, BROWS, 0, stream>>>(bucket_base, part, row_ptr, col_val);

    // 3 pull-based SpMM layers; layer 3 fuses the final mean
    const int rows_per_block = B / 64;
    const int grid_spmm = (N_NODES + rows_per_block - 1) / rows_per_block;
    for (int l = 0; l < 3; ++l) {
        unsigned int* xq_in  = xq[l & 1];
        unsigned int* xq_out = (l < 2) ? xq[(l + 1) & 1] : nullptr;
        bool last = (l == 2);
        spmm_fp8_kernel<<<grid_spmm, B, 0, stream>>>(
            row_ptr, col_val, xq_in, slot[l + 1], xq_out,
            last ? (const float4*)slot[0] : nullptr,
            last ? (const float4*)slot[1] : nullptr,
            last ? (const float4*)slot[2] : nullptr,
            last ? (float4*)final_emb : nullptr);
    }
}

// Round 11
// 479.488 us; speedup vs baseline: 1.4444x; 1.4444x over previous
//
#include <hip/hip_runtime.h>
#include <hip/hip_bf16.h>

// LightGCN encoder — round 11 (round 10 minus nontemporal hints):
//   * round-10 lesson: NT stores bypass L2 write-coalescing -> 5x write amp
//     on the partition scatter (53 -> 258 MB). Plain stores restore L2 merging.
//   * partition: 1024-thread blocks, EPT 16, tile 16384 edges (round-8 run
//     length, round-9 TLP), rows register-cached, val quantized to 14b
//   * keep: fused copy_hist, 4B packed edges, spmm main/tail + 32-bit
//     addressing, fused final mean
//
// d_out layout (floats):
//   [0 .. 9.6M)    : final (users ‖ items)
//   [9.6M .. 48M)  : stacked slots 0..3 -- slot1/2 double as `part` scratch
// d_ws: row_ptr | col_val(u32) | bucket_cnt | bucket_base | bucket_cursor | xq0 | xq1

constexpr int N_USERS = 100000;
constexpr int N_ITEMS = 50000;
constexpr int N_NODES = N_USERS + N_ITEMS;   // 150000
constexpr int EMB     = 64;
constexpr int NNZ     = 6000000;
constexpr long long NODE_ELEMS = (long long)N_NODES * EMB;  // 9,600,000
constexpr float SCALE     = 64.0f;
constexpr float INV_SCALE = 1.0f / 64.0f;
constexpr float VMAX      = 0.05f;
constexpr float VENC      = 16383.0f / VMAX;
constexpr float VDEC      = VMAX / 16383.0f;

constexpr int BSHIFT = 10;                    // 1024 rows per bucket
constexpr int BROWS  = 1 << BSHIFT;           // 1024
constexpr int NBUCK  = (N_NODES + BROWS - 1) / BROWS;  // 147

constexpr int COPY_BLOCKS = (int)((NODE_ELEMS / 4 + 255) / 256);   // 9375
constexpr int HIST_EPT = 16;
constexpr int HIST_BLOCKS = (NNZ + 256 * HIST_EPT - 1) / (256 * HIST_EPT);  // 1465

// ---- fp8 e4m3 pack/unpack via gfx950 HW converts ----
__device__ __forceinline__ unsigned int enc_fp8x4(float a, float b, float c, float d) {
    int r = 0;
    r = __builtin_amdgcn_cvt_pk_fp8_f32(a, b, r, false);
    r = __builtin_amdgcn_cvt_pk_fp8_f32(c, d, r, true);
    return (unsigned int)r;
}
__device__ __forceinline__ float4 dec_fp8x4(unsigned int u) {
    auto lo = __builtin_amdgcn_cvt_pk_f32_fp8((int)u, false);
    auto hi = __builtin_amdgcn_cvt_pk_f32_fp8((int)u, true);
    return make_float4(lo[0], lo[1], hi[0], hi[1]);
}

// ---- zero the bucket counters ----
__global__ void zero_buckets_kernel(int* __restrict__ p) {
    int t = threadIdx.x;
    if (t < NBUCK) p[t] = 0;
}

// ---- fused: emb0 copy (+fp8 encode) ‖ bucket histogram ----
__global__ void copy_hist_kernel(const float* __restrict__ user_emb,
                                 const float* __restrict__ item_emb,
                                 float* __restrict__ slot0,
                                 unsigned int* __restrict__ xq0,
                                 const int* __restrict__ rows,
                                 int* __restrict__ bucket_cnt) {
    if (blockIdx.x < COPY_BLOCKS) {
        long long i4 = (long long)blockIdx.x * 256 + threadIdx.x;
        long long n4 = NODE_ELEMS / 4;
        if (i4 >= n4) return;
        long long i = i4 * 4;
        const long long user_elems = (long long)N_USERS * EMB;
        float4 v;
        if (i < user_elems) {
            v = *reinterpret_cast<const float4*>(user_emb + i);
        } else {
            v = *reinterpret_cast<const float4*>(item_emb + (i - user_elems));
        }
        *reinterpret_cast<float4*>(slot0 + i) = v;
        xq0[i4] = enc_fp8x4(v.x * SCALE, v.y * SCALE, v.z * SCALE, v.w * SCALE);
    } else {
        __shared__ int lcnt[NBUCK];
        int bid = blockIdx.x - COPY_BLOCKS;
        int tid = threadIdx.x;
        for (int i = tid; i < NBUCK; i += 256) lcnt[i] = 0;
        __syncthreads();
        long long base = (long long)bid * 256 * HIST_EPT;
        for (int k = 0; k < HIST_EPT; ++k) {
            long long e = base + (long long)k * 256 + tid;
            if (e < NNZ) atomicAdd(&lcnt[rows[e] >> BSHIFT], 1);
        }
        __syncthreads();
        for (int i = tid; i < NBUCK; i += 256) {
            int c = lcnt[i];
            if (c) atomicAdd(&bucket_cnt[i], c);
        }
    }
}

// ---- bucket scan: base/cursor init + row_ptr[N_NODES] ----
__global__ void bucket_scan_kernel(const int* __restrict__ bucket_cnt,
                                   int* __restrict__ bucket_base,
                                   int* __restrict__ bucket_cursor,
                                   int* __restrict__ row_ptr) {
    __shared__ int s[256];
    int t = threadIdx.x;
    s[t] = (t < NBUCK) ? bucket_cnt[t] : 0;
    __syncthreads();
    int orig = s[t];
    for (int off = 1; off < 256; off <<= 1) {
        int v = (t >= off) ? s[t - off] : 0;
        __syncthreads();
        s[t] += v;
        __syncthreads();
    }
    int excl = s[t] - orig;
    if (t < NBUCK) {
        bucket_base[t] = excl;
        bucket_cursor[t] = excl;
    }
    if (t == NBUCK - 1) bucket_base[NBUCK] = s[t];
    if (t == 0) row_ptr[N_NODES] = NNZ;
}

// ---- pass A: multi-split partition into row-buckets ----
// part[] entry (u64): low32 = (rowoff<<18) | col, high32 = q (14-bit val)
// tile = 16384 edges (minimal write-amp) via 1024 thr x EPT 16 (TLP)
constexpr int PART_T   = 1024;
constexpr int PART_EPT = 16;
__global__ __launch_bounds__(PART_T) void partition_kernel(
        const int* __restrict__ rows,
        const int* __restrict__ cols,
        const float* __restrict__ vals,
        int* __restrict__ bucket_cursor,
        unsigned long long* __restrict__ part) {
    __shared__ int lcnt[NBUCK];
    __shared__ int lcur[NBUCK];
    int tid = threadIdx.x;
    for (int i = tid; i < NBUCK; i += PART_T) lcnt[i] = 0;
    __syncthreads();
    long long tbase = (long long)blockIdx.x * PART_T * PART_EPT;
    int rloc[PART_EPT];
#pragma unroll
    for (int k = 0; k < PART_EPT; ++k) {
        long long e = tbase + (long long)k * PART_T + tid;
        int r = (e < NNZ) ? rows[e] : -1;
        rloc[k] = r;
        if (r >= 0) atomicAdd(&lcnt[r >> BSHIFT], 1);
    }
    __syncthreads();
    for (int i = tid; i < NBUCK; i += PART_T) {
        lcur[i] = atomicAdd(&bucket_cursor[i], lcnt[i]);
    }
    __syncthreads();
#pragma unroll
    for (int k = 0; k < PART_EPT; ++k) {
        int r = rloc[k];
        if (r < 0) continue;
        long long e = tbase + (long long)k * PART_T + tid;
        int b = r >> BSHIFT;
        int pos = atomicAdd(&lcur[b], 1);
        unsigned int w0 = ((unsigned int)(r & (BROWS - 1)) << 18) | (unsigned int)cols[e];
        unsigned int q = (unsigned int)(int)(fminf(fmaxf(vals[e] * VENC + 0.5f, 0.0f), 16383.0f));
        part[pos] = ((unsigned long long)q << 32) | (unsigned long long)w0;
    }
}

// ---- pass B: per-bucket counting sort -> final CSR (packed 4B edges) ----
__global__ __launch_bounds__(BROWS) void bucket_sort_kernel(
        const int* __restrict__ bucket_base,
        const unsigned long long* __restrict__ part,
        int* __restrict__ row_ptr,
        unsigned int* __restrict__ col_val) {
    __shared__ int lcnt[BROWS];
    __shared__ int lcur[BROWS];
    int b = blockIdx.x;
    int t = threadIdx.x;
    int base = bucket_base[b];
    int n    = bucket_base[b + 1] - base;
    lcnt[t] = 0;
    __syncthreads();
    for (int j = t; j < n; j += BROWS) {
        unsigned int w0 = (unsigned int)part[base + j];
        atomicAdd(&lcnt[w0 >> 18], 1);
    }
    __syncthreads();
    int orig = lcnt[t];
    for (int off = 1; off < BROWS; off <<= 1) {
        int v = (t >= off) ? lcnt[t - off] : 0;
        __syncthreads();
        lcnt[t] += v;
        __syncthreads();
    }
    int excl = lcnt[t] - orig;
    int gr = b * BROWS + t;
    if (gr < N_NODES) row_ptr[gr] = base + excl;
    lcur[t] = base + excl;
    __syncthreads();
    for (int j = t; j < n; j += BROWS) {
        unsigned long long w = part[base + j];
        unsigned int w0 = (unsigned int)w;
        unsigned int q  = (unsigned int)(w >> 32);
        int rowoff = (int)(w0 >> 18);
        unsigned int col = w0 & 0x3FFFFu;
        int pos = atomicAdd(&lcur[rowoff], 1);
        col_val[pos] = (col << 14) | q;
    }
}

// ---- pull-based CSR SpMM, fp8 gathers, main/tail split, f32 accumulate ----
// wave per row; lane = (edge-slot g 0..3, dim-word d4 0..15)
// If `fin` != nullptr (layer 3): also compute final = (s0+s1+s2+y)/4.
__global__ void spmm_fp8_kernel(const int* __restrict__ row_ptr,
                                const unsigned int* __restrict__ col_val,
                                const unsigned int* __restrict__ xq_in,  // 16 words/row
                                float* __restrict__ y,
                                unsigned int* __restrict__ xq_out,
                                const float4* __restrict__ s0,
                                const float4* __restrict__ s1,
                                const float4* __restrict__ s2,
                                float4* __restrict__ fin) {
    int row = blockIdx.x * (blockDim.x >> 6) + (threadIdx.x >> 6);
    int lane = threadIdx.x & 63;
    int g  = lane >> 4;   // edge sub-slot
    int d4 = lane & 15;   // 4-dim word index
    if (row >= N_NODES) return;
    int s = row_ptr[row];
    int e = row_ptr[row + 1];
    float4 acc = make_float4(0.f, 0.f, 0.f, 0.f);
    int i = s;
    // main: full 32-edge iterations, no bounds checks
    for (; i + 32 <= e; i += 32) {
        unsigned int cv[8];
        unsigned int q[8];
#pragma unroll
        for (int k = 0; k < 8; ++k) cv[k] = col_val[i + 4 * k + g];
#pragma unroll
        for (int k = 0; k < 8; ++k) q[k] = xq_in[((cv[k] >> 14) << 4) | d4];
#pragma unroll
        for (int k = 0; k < 8; ++k) {
            float v = (float)(cv[k] & 0x3FFFu) * VDEC;
            float4 x = dec_fp8x4(q[k]);
            acc.x += v * x.x; acc.y += v * x.y; acc.z += v * x.z; acc.w += v * x.w;
        }
    }
    // tail: 16-edge iterations, predicated (dummy slots read row 0, val 0)
    for (; i < e; i += 16) {
        unsigned int cv[4];
        unsigned int q[4];
#pragma unroll
        for (int k = 0; k < 4; ++k) {
            int idx = i + 4 * k + g;
            cv[k] = (idx < e) ? col_val[idx] : 0u;
        }
#pragma unroll
        for (int k = 0; k < 4; ++k) q[k] = xq_in[((cv[k] >> 14) << 4) | d4];
#pragma unroll
        for (int k = 0; k < 4; ++k) {
            float v = (float)(cv[k] & 0x3FFFu) * VDEC;
            float4 x = dec_fp8x4(q[k]);
            acc.x += v * x.x; acc.y += v * x.y; acc.z += v * x.z; acc.w += v * x.w;
        }
    }
    // sum the 4 edge-slot partials (lanes differing in bits 4,5)
    acc.x += __shfl_xor(acc.x, 16); acc.y += __shfl_xor(acc.y, 16);
    acc.z += __shfl_xor(acc.z, 16); acc.w += __shfl_xor(acc.w, 16);
    acc.x += __shfl_xor(acc.x, 32); acc.y += __shfl_xor(acc.y, 32);
    acc.z += __shfl_xor(acc.z, 32); acc.w += __shfl_xor(acc.w, 32);
    if (g == 0) {
        long long o = (long long)row * 16 + d4;  // float4 index
        float4 r;
        r.x = acc.x * INV_SCALE;
        r.y = acc.y * INV_SCALE;
        r.z = acc.z * INV_SCALE;
        r.w = acc.w * INV_SCALE;
        reinterpret_cast<float4*>(y)[o] = r;
        if (xq_out) xq_out[o] = enc_fp8x4(acc.x, acc.y, acc.z, acc.w);
        if (fin) {
            float4 a = s0[o], b = s1[o], c = s2[o];
            float4 f;
            f.x = (a.x + b.x + c.x + r.x) * 0.25f;
            f.y = (a.y + b.y + c.y + r.y) * 0.25f;
            f.z = (a.z + b.z + c.z + r.z) * 0.25f;
            f.w = (a.w + b.w + c.w + r.w) * 0.25f;
            fin[o] = f;
        }
    }
}

extern "C" void kernel_launch(void* const* d_in, const int* in_sizes, int n_in,
                              void* d_out, int out_size, void* d_ws, size_t ws_size,
                              hipStream_t stream) {
    const float* user_emb = (const float*)d_in[0];
    const float* item_emb = (const float*)d_in[1];
    const int*   adj_rows = (const int*)d_in[2];
    const int*   adj_cols = (const int*)d_in[3];
    const float* adj_vals = (const float*)d_in[4];

    float* out = (float*)d_out;
    float* final_emb = out;
    float* stacked   = out + NODE_ELEMS;
    float* slot[4];
    for (int l = 0; l < 4; ++l) slot[l] = stacked + (long long)l * NODE_ELEMS;

    // `part` buffer (48MB) aliases slot1+slot2 (76.8MB), dead until SpMM layer 0
    unsigned long long* part = (unsigned long long*)slot[1];

    // workspace carve-up (16B-aligned)
    size_t off = 0;
    auto carve = [&](size_t bytes) { size_t o = off; off += (bytes + 15) & ~(size_t)15; return o; };
    size_t o_rp = carve((size_t)(N_NODES + 1) * 4);
    size_t o_cv = carve((size_t)NNZ * 4);
    size_t o_bc = carve((size_t)NBUCK * 4);
    size_t o_bb = carve((size_t)(NBUCK + 1) * 4);
    size_t o_bu = carve((size_t)NBUCK * 4);
    size_t o_x0 = carve((size_t)(NODE_ELEMS / 4) * 4);
    size_t o_x1 = carve((size_t)(NODE_ELEMS / 4) * 4);
    char* ws = (char*)d_ws;
    int*          row_ptr       = (int*)(ws + o_rp);
    unsigned int* col_val       = (unsigned int*)(ws + o_cv);
    int*          bucket_cnt    = (int*)(ws + o_bc);
    int*          bucket_base   = (int*)(ws + o_bb);
    int*          bucket_cursor = (int*)(ws + o_bu);
    unsigned int* xq[2];
    xq[0] = (unsigned int*)(ws + o_x0);
    xq[1] = (unsigned int*)(ws + o_x1);

    const int B = 256;

    // zero bucket counters, then fused emb0-copy ‖ bucket histogram
    zero_buckets_kernel<<<1, 256, 0, stream>>>(bucket_cnt);
    copy_hist_kernel<<<COPY_BLOCKS + HIST_BLOCKS, B, 0, stream>>>(
        user_emb, item_emb, slot[0], xq[0], adj_rows, bucket_cnt);

    // scan -> partition -> per-bucket sort
    bucket_scan_kernel<<<1, 256, 0, stream>>>(bucket_cnt, bucket_base, bucket_cursor, row_ptr);
    const int part_grid = (NNZ + PART_T * PART_EPT - 1) / (PART_T * PART_EPT);
    partition_kernel<<<part_grid, PART_T, 0, stream>>>(
        adj_rows, adj_cols, adj_vals, bucket_cursor, part);
    bucket_sort_kernel<<<NBUCK, BROWS, 0, stream>>>(bucket_base, part, row_ptr, col_val);

    // 3 pull-based SpMM layers; layer 3 fuses the final mean
    const int rows_per_block = B / 64;
    const int grid_spmm = (N_NODES + rows_per_block - 1) / rows_per_block;
    for (int l = 0; l < 3; ++l) {
        unsigned int* xq_in  = xq[l & 1];
        unsigned int* xq_out = (l < 2) ? xq[(l + 1) & 1] : nullptr;
        bool last = (l == 2);
        spmm_fp8_kernel<<<grid_spmm, B, 0, stream>>>(
            row_ptr, col_val, xq_in, slot[l + 1], xq_out,
            last ? (const float4*)slot[0] : nullptr,
            last ? (const float4*)slot[1] : nullptr,
            last ? (const float4*)slot[2] : nullptr,
            last ? (float4*)final_emb : nullptr);
    }
}

// Round 12
// 478.293 us; speedup vs baseline: 1.4480x; 1.0025x over previous
//
#include <hip/hip_runtime.h>
#include <hip/hip_bf16.h>

// LightGCN encoder — round 12 (round 11 + dual-row SpMM):
//   * spmm: each wave owns TWO rows; joint 8-deep main loop -> 16 outstanding
//     gathers/lane (was 8) to attack the L2-miss latency bound (r11: 45%
//     VALUBusy, 3.2 TB/s, latency-bound). Single-row mains for imbalance +
//     joint predicated tail.
//   * everything else identical to round 11 (known-good: 479 us).
//
// d_out layout (floats):
//   [0 .. 9.6M)    : final (users ‖ items)
//   [9.6M .. 48M)  : stacked slots 0..3 -- slot1/2 double as `part` scratch
// d_ws: row_ptr | col_val(u32) | bucket_cnt | bucket_base | bucket_cursor | xq0 | xq1

constexpr int N_USERS = 100000;
constexpr int N_ITEMS = 50000;
constexpr int N_NODES = N_USERS + N_ITEMS;   // 150000
constexpr int EMB     = 64;
constexpr int NNZ     = 6000000;
constexpr long long NODE_ELEMS = (long long)N_NODES * EMB;  // 9,600,000
constexpr float SCALE     = 64.0f;
constexpr float INV_SCALE = 1.0f / 64.0f;
constexpr float VMAX      = 0.05f;
constexpr float VENC      = 16383.0f / VMAX;
constexpr float VDEC      = VMAX / 16383.0f;

constexpr int BSHIFT = 10;                    // 1024 rows per bucket
constexpr int BROWS  = 1 << BSHIFT;           // 1024
constexpr int NBUCK  = (N_NODES + BROWS - 1) / BROWS;  // 147

constexpr int COPY_BLOCKS = (int)((NODE_ELEMS / 4 + 255) / 256);   // 9375
constexpr int HIST_EPT = 16;
constexpr int HIST_BLOCKS = (NNZ + 256 * HIST_EPT - 1) / (256 * HIST_EPT);  // 1465

// ---- fp8 e4m3 pack/unpack via gfx950 HW converts ----
__device__ __forceinline__ unsigned int enc_fp8x4(float a, float b, float c, float d) {
    int r = 0;
    r = __builtin_amdgcn_cvt_pk_fp8_f32(a, b, r, false);
    r = __builtin_amdgcn_cvt_pk_fp8_f32(c, d, r, true);
    return (unsigned int)r;
}
__device__ __forceinline__ float4 dec_fp8x4(unsigned int u) {
    auto lo = __builtin_amdgcn_cvt_pk_f32_fp8((int)u, false);
    auto hi = __builtin_amdgcn_cvt_pk_f32_fp8((int)u, true);
    return make_float4(lo[0], lo[1], hi[0], hi[1]);
}

// ---- zero the bucket counters ----
__global__ void zero_buckets_kernel(int* __restrict__ p) {
    int t = threadIdx.x;
    if (t < NBUCK) p[t] = 0;
}

// ---- fused: emb0 copy (+fp8 encode) ‖ bucket histogram ----
__global__ void copy_hist_kernel(const float* __restrict__ user_emb,
                                 const float* __restrict__ item_emb,
                                 float* __restrict__ slot0,
                                 unsigned int* __restrict__ xq0,
                                 const int* __restrict__ rows,
                                 int* __restrict__ bucket_cnt) {
    if (blockIdx.x < COPY_BLOCKS) {
        long long i4 = (long long)blockIdx.x * 256 + threadIdx.x;
        long long n4 = NODE_ELEMS / 4;
        if (i4 >= n4) return;
        long long i = i4 * 4;
        const long long user_elems = (long long)N_USERS * EMB;
        float4 v;
        if (i < user_elems) {
            v = *reinterpret_cast<const float4*>(user_emb + i);
        } else {
            v = *reinterpret_cast<const float4*>(item_emb + (i - user_elems));
        }
        *reinterpret_cast<float4*>(slot0 + i) = v;
        xq0[i4] = enc_fp8x4(v.x * SCALE, v.y * SCALE, v.z * SCALE, v.w * SCALE);
    } else {
        __shared__ int lcnt[NBUCK];
        int bid = blockIdx.x - COPY_BLOCKS;
        int tid = threadIdx.x;
        for (int i = tid; i < NBUCK; i += 256) lcnt[i] = 0;
        __syncthreads();
        long long base = (long long)bid * 256 * HIST_EPT;
        for (int k = 0; k < HIST_EPT; ++k) {
            long long e = base + (long long)k * 256 + tid;
            if (e < NNZ) atomicAdd(&lcnt[rows[e] >> BSHIFT], 1);
        }
        __syncthreads();
        for (int i = tid; i < NBUCK; i += 256) {
            int c = lcnt[i];
            if (c) atomicAdd(&bucket_cnt[i], c);
        }
    }
}

// ---- bucket scan: base/cursor init + row_ptr[N_NODES] ----
__global__ void bucket_scan_kernel(const int* __restrict__ bucket_cnt,
                                   int* __restrict__ bucket_base,
                                   int* __restrict__ bucket_cursor,
                                   int* __restrict__ row_ptr) {
    __shared__ int s[256];
    int t = threadIdx.x;
    s[t] = (t < NBUCK) ? bucket_cnt[t] : 0;
    __syncthreads();
    int orig = s[t];
    for (int off = 1; off < 256; off <<= 1) {
        int v = (t >= off) ? s[t - off] : 0;
        __syncthreads();
        s[t] += v;
        __syncthreads();
    }
    int excl = s[t] - orig;
    if (t < NBUCK) {
        bucket_base[t] = excl;
        bucket_cursor[t] = excl;
    }
    if (t == NBUCK - 1) bucket_base[NBUCK] = s[t];
    if (t == 0) row_ptr[N_NODES] = NNZ;
}

// ---- pass A: multi-split partition into row-buckets ----
// part[] entry (u64): low32 = (rowoff<<18) | col, high32 = q (14-bit val)
constexpr int PART_T   = 1024;
constexpr int PART_EPT = 16;
__global__ __launch_bounds__(PART_T) void partition_kernel(
        const int* __restrict__ rows,
        const int* __restrict__ cols,
        const float* __restrict__ vals,
        int* __restrict__ bucket_cursor,
        unsigned long long* __restrict__ part) {
    __shared__ int lcnt[NBUCK];
    __shared__ int lcur[NBUCK];
    int tid = threadIdx.x;
    for (int i = tid; i < NBUCK; i += PART_T) lcnt[i] = 0;
    __syncthreads();
    long long tbase = (long long)blockIdx.x * PART_T * PART_EPT;
    int rloc[PART_EPT];
#pragma unroll
    for (int k = 0; k < PART_EPT; ++k) {
        long long e = tbase + (long long)k * PART_T + tid;
        int r = (e < NNZ) ? rows[e] : -1;
        rloc[k] = r;
        if (r >= 0) atomicAdd(&lcnt[r >> BSHIFT], 1);
    }
    __syncthreads();
    for (int i = tid; i < NBUCK; i += PART_T) {
        lcur[i] = atomicAdd(&bucket_cursor[i], lcnt[i]);
    }
    __syncthreads();
#pragma unroll
    for (int k = 0; k < PART_EPT; ++k) {
        int r = rloc[k];
        if (r < 0) continue;
        long long e = tbase + (long long)k * PART_T + tid;
        int b = r >> BSHIFT;
        int pos = atomicAdd(&lcur[b], 1);
        unsigned int w0 = ((unsigned int)(r & (BROWS - 1)) << 18) | (unsigned int)cols[e];
        unsigned int q = (unsigned int)(int)(fminf(fmaxf(vals[e] * VENC + 0.5f, 0.0f), 16383.0f));
        part[pos] = ((unsigned long long)q << 32) | (unsigned long long)w0;
    }
}

// ---- pass B: per-bucket counting sort -> final CSR (packed 4B edges) ----
__global__ __launch_bounds__(BROWS) void bucket_sort_kernel(
        const int* __restrict__ bucket_base,
        const unsigned long long* __restrict__ part,
        int* __restrict__ row_ptr,
        unsigned int* __restrict__ col_val) {
    __shared__ int lcnt[BROWS];
    __shared__ int lcur[BROWS];
    int b = blockIdx.x;
    int t = threadIdx.x;
    int base = bucket_base[b];
    int n    = bucket_base[b + 1] - base;
    lcnt[t] = 0;
    __syncthreads();
    for (int j = t; j < n; j += BROWS) {
        unsigned int w0 = (unsigned int)part[base + j];
        atomicAdd(&lcnt[w0 >> 18], 1);
    }
    __syncthreads();
    int orig = lcnt[t];
    for (int off = 1; off < BROWS; off <<= 1) {
        int v = (t >= off) ? lcnt[t - off] : 0;
        __syncthreads();
        lcnt[t] += v;
        __syncthreads();
    }
    int excl = lcnt[t] - orig;
    int gr = b * BROWS + t;
    if (gr < N_NODES) row_ptr[gr] = base + excl;
    lcur[t] = base + excl;
    __syncthreads();
    for (int j = t; j < n; j += BROWS) {
        unsigned long long w = part[base + j];
        unsigned int w0 = (unsigned int)w;
        unsigned int q  = (unsigned int)(w >> 32);
        int rowoff = (int)(w0 >> 18);
        unsigned int col = w0 & 0x3FFFFu;
        int pos = atomicAdd(&lcur[rowoff], 1);
        col_val[pos] = (col << 14) | q;
    }
}

// ---- dual-row pull-based CSR SpMM, fp8 gathers, f32 accumulate ----
// wave owns rows {2w, 2w+1}; lane = (edge-slot g 0..3, dim-word d4 0..15)
// If `fin` != nullptr (layer 3): also compute final = (s0+s1+s2+y)/4.
#define FMA4(A, V, X) \
    A.x += (V) * (X).x; A.y += (V) * (X).y; A.z += (V) * (X).z; A.w += (V) * (X).w;

__global__ void spmm_fp8_kernel(const int* __restrict__ row_ptr,
                                const unsigned int* __restrict__ col_val,
                                const unsigned int* __restrict__ xq_in,  // 16 words/row
                                float* __restrict__ y,
                                unsigned int* __restrict__ xq_out,
                                const float4* __restrict__ s0,
                                const float4* __restrict__ s1,
                                const float4* __restrict__ s2,
                                float4* __restrict__ fin) {
    int wid = blockIdx.x * (blockDim.x >> 6) + (threadIdx.x >> 6);
    int lane = threadIdx.x & 63;
    int g  = lane >> 4;   // edge sub-slot
    int d4 = lane & 15;   // 4-dim word index
    int row0 = wid * 2;
    int row1 = row0 + 1;
    if (row0 >= N_NODES) return;
    int i0 = row_ptr[row0], e0 = row_ptr[row0 + 1];
    int i1 = 0, e1 = 0;
    if (row1 < N_NODES) { i1 = row_ptr[row1]; e1 = row_ptr[row1 + 1]; }
    float4 a0 = make_float4(0.f, 0.f, 0.f, 0.f);
    float4 a1 = make_float4(0.f, 0.f, 0.f, 0.f);

    // joint main: both rows full 32-edge blocks -> 16 outstanding gathers/lane
    while (i0 + 32 <= e0 && i1 + 32 <= e1) {
        unsigned int cv0[8], cv1[8], q0[8], q1[8];
#pragma unroll
        for (int k = 0; k < 8; ++k) {
            cv0[k] = col_val[i0 + 4 * k + g];
            cv1[k] = col_val[i1 + 4 * k + g];
        }
#pragma unroll
        for (int k = 0; k < 8; ++k) {
            q0[k] = xq_in[((cv0[k] >> 14) << 4) | d4];
            q1[k] = xq_in[((cv1[k] >> 14) << 4) | d4];
        }
#pragma unroll
        for (int k = 0; k < 8; ++k) {
            float v0 = (float)(cv0[k] & 0x3FFFu) * VDEC;
            float4 x0 = dec_fp8x4(q0[k]);
            FMA4(a0, v0, x0);
            float v1 = (float)(cv1[k] & 0x3FFFu) * VDEC;
            float4 x1 = dec_fp8x4(q1[k]);
            FMA4(a1, v1, x1);
        }
        i0 += 32; i1 += 32;
    }
    // single-row mains (imbalance)
    for (; i0 + 32 <= e0; i0 += 32) {
        unsigned int cv[8], q[8];
#pragma unroll
        for (int k = 0; k < 8; ++k) cv[k] = col_val[i0 + 4 * k + g];
#pragma unroll
        for (int k = 0; k < 8; ++k) q[k] = xq_in[((cv[k] >> 14) << 4) | d4];
#pragma unroll
        for (int k = 0; k < 8; ++k) {
            float v = (float)(cv[k] & 0x3FFFu) * VDEC;
            float4 x = dec_fp8x4(q[k]);
            FMA4(a0, v, x);
        }
    }
    for (; i1 + 32 <= e1; i1 += 32) {
        unsigned int cv[8], q[8];
#pragma unroll
        for (int k = 0; k < 8; ++k) cv[k] = col_val[i1 + 4 * k + g];
#pragma unroll
        for (int k = 0; k < 8; ++k) q[k] = xq_in[((cv[k] >> 14) << 4) | d4];
#pragma unroll
        for (int k = 0; k < 8; ++k) {
            float v = (float)(cv[k] & 0x3FFFu) * VDEC;
            float4 x = dec_fp8x4(q[k]);
            FMA4(a1, v, x);
        }
    }
    // joint predicated tail (16 edges per row per iter)
    while (i0 < e0 || i1 < e1) {
        unsigned int cv0[4], cv1[4], q0[4], q1[4];
#pragma unroll
        for (int k = 0; k < 4; ++k) {
            int x0 = i0 + 4 * k + g;
            int x1 = i1 + 4 * k + g;
            cv0[k] = (x0 < e0) ? col_val[x0] : 0u;
            cv1[k] = (x1 < e1) ? col_val[x1] : 0u;
        }
#pragma unroll
        for (int k = 0; k < 4; ++k) {
            q0[k] = xq_in[((cv0[k] >> 14) << 4) | d4];
            q1[k] = xq_in[((cv1[k] >> 14) << 4) | d4];
        }
#pragma unroll
        for (int k = 0; k < 4; ++k) {
            float v0 = (float)(cv0[k] & 0x3FFFu) * VDEC;
            float4 x0 = dec_fp8x4(q0[k]);
            FMA4(a0, v0, x0);
            float v1 = (float)(cv1[k] & 0x3FFFu) * VDEC;
            float4 x1 = dec_fp8x4(q1[k]);
            FMA4(a1, v1, x1);
        }
        i0 += 16; i1 += 16;
    }

    // reduce the 4 edge-slot partials (lanes differing in bits 4,5)
    a0.x += __shfl_xor(a0.x, 16); a0.y += __shfl_xor(a0.y, 16);
    a0.z += __shfl_xor(a0.z, 16); a0.w += __shfl_xor(a0.w, 16);
    a0.x += __shfl_xor(a0.x, 32); a0.y += __shfl_xor(a0.y, 32);
    a0.z += __shfl_xor(a0.z, 32); a0.w += __shfl_xor(a0.w, 32);
    a1.x += __shfl_xor(a1.x, 16); a1.y += __shfl_xor(a1.y, 16);
    a1.z += __shfl_xor(a1.z, 16); a1.w += __shfl_xor(a1.w, 16);
    a1.x += __shfl_xor(a1.x, 32); a1.y += __shfl_xor(a1.y, 32);
    a1.z += __shfl_xor(a1.z, 32); a1.w += __shfl_xor(a1.w, 32);

    if (g == 0) {
        long long o0 = (long long)row0 * 16 + d4;  // float4 index
        float4 r0;
        r0.x = a0.x * INV_SCALE; r0.y = a0.y * INV_SCALE;
        r0.z = a0.z * INV_SCALE; r0.w = a0.w * INV_SCALE;
        reinterpret_cast<float4*>(y)[o0] = r0;
        if (xq_out) xq_out[o0] = enc_fp8x4(a0.x, a0.y, a0.z, a0.w);
        if (fin) {
            float4 a = s0[o0], b = s1[o0], c = s2[o0];
            float4 f;
            f.x = (a.x + b.x + c.x + r0.x) * 0.25f;
            f.y = (a.y + b.y + c.y + r0.y) * 0.25f;
            f.z = (a.z + b.z + c.z + r0.z) * 0.25f;
            f.w = (a.w + b.w + c.w + r0.w) * 0.25f;
            fin[o0] = f;
        }
        if (row1 < N_NODES) {
            long long o1 = (long long)row1 * 16 + d4;
            float4 r1;
            r1.x = a1.x * INV_SCALE; r1.y = a1.y * INV_SCALE;
            r1.z = a1.z * INV_SCALE; r1.w = a1.w * INV_SCALE;
            reinterpret_cast<float4*>(y)[o1] = r1;
            if (xq_out) xq_out[o1] = enc_fp8x4(a1.x, a1.y, a1.z, a1.w);
            if (fin) {
                float4 a = s0[o1], b = s1[o1], c = s2[o1];
                float4 f;
                f.x = (a.x + b.x + c.x + r1.x) * 0.25f;
                f.y = (a.y + b.y + c.y + r1.y) * 0.25f;
                f.z = (a.z + b.z + c.z + r1.z) * 0.25f;
                f.w = (a.w + b.w + c.w + r1.w) * 0.25f;
                fin[o1] = f;
            }
        }
    }
}

extern "C" void kernel_launch(void* const* d_in, const int* in_sizes, int n_in,
                              void* d_out, int out_size, void* d_ws, size_t ws_size,
                              hipStream_t stream) {
    const float* user_emb = (const float*)d_in[0];
    const float* item_emb = (const float*)d_in[1];
    const int*   adj_rows = (const int*)d_in[2];
    const int*   adj_cols = (const int*)d_in[3];
    const float* adj_vals = (const float*)d_in[4];

    float* out = (float*)d_out;
    float* final_emb = out;
    float* stacked   = out + NODE_ELEMS;
    float* slot[4];
    for (int l = 0; l < 4; ++l) slot[l] = stacked + (long long)l * NODE_ELEMS;

    // `part` buffer (48MB) aliases slot1+slot2 (76.8MB), dead until SpMM layer 0
    unsigned long long* part = (unsigned long long*)slot[1];

    // workspace carve-up (16B-aligned)
    size_t off = 0;
    auto carve = [&](size_t bytes) { size_t o = off; off += (bytes + 15) & ~(size_t)15; return o; };
    size_t o_rp = carve((size_t)(N_NODES + 1) * 4);
    size_t o_cv = carve((size_t)NNZ * 4);
    size_t o_bc = carve((size_t)NBUCK * 4);
    size_t o_bb = carve((size_t)(NBUCK + 1) * 4);
    size_t o_bu = carve((size_t)NBUCK * 4);
    size_t o_x0 = carve((size_t)(NODE_ELEMS / 4) * 4);
    size_t o_x1 = carve((size_t)(NODE_ELEMS / 4) * 4);
    char* ws = (char*)d_ws;
    int*          row_ptr       = (int*)(ws + o_rp);
    unsigned int* col_val       = (unsigned int*)(ws + o_cv);
    int*          bucket_cnt    = (int*)(ws + o_bc);
    int*          bucket_base   = (int*)(ws + o_bb);
    int*          bucket_cursor = (int*)(ws + o_bu);
    unsigned int* xq[2];
    xq[0] = (unsigned int*)(ws + o_x0);
    xq[1] = (unsigned int*)(ws + o_x1);

    const int B = 256;

    // zero bucket counters, then fused emb0-copy ‖ bucket histogram
    zero_buckets_kernel<<<1, 256, 0, stream>>>(bucket_cnt);
    copy_hist_kernel<<<COPY_BLOCKS + HIST_BLOCKS, B, 0, stream>>>(
        user_emb, item_emb, slot[0], xq[0], adj_rows, bucket_cnt);

    // scan -> partition -> per-bucket sort
    bucket_scan_kernel<<<1, 256, 0, stream>>>(bucket_cnt, bucket_base, bucket_cursor, row_ptr);
    const int part_grid = (NNZ + PART_T * PART_EPT - 1) / (PART_T * PART_EPT);
    partition_kernel<<<part_grid, PART_T, 0, stream>>>(
        adj_rows, adj_cols, adj_vals, bucket_cursor, part);
    bucket_sort_kernel<<<NBUCK, BROWS, 0, stream>>>(bucket_base, part, row_ptr, col_val);

    // 3 dual-row SpMM layers; layer 3 fuses the final mean
    const int waves_per_block = B / 64;                 // 4
    const int rows_per_block  = waves_per_block * 2;    // 8
    const int grid_spmm = (N_NODES + rows_per_block - 1) / rows_per_block;
    for (int l = 0; l < 3; ++l) {
        unsigned int* xq_in  = xq[l & 1];
        unsigned int* xq_out = (l < 2) ? xq[(l + 1) & 1] : nullptr;
        bool last = (l == 2);
        spmm_fp8_kernel<<<grid_spmm, B, 0, stream>>>(
            row_ptr, col_val, xq_in, slot[l + 1], xq_out,
            last ? (const float4*)slot[0] : nullptr,
            last ? (const float4*)slot[1] : nullptr,
            last ? (const float4*)slot[2] : nullptr,
            last ? (float4*)final_emb : nullptr);
    }
}